// Round 6
// baseline (181.827 us; speedup 1.0000x reference)
//
#include <hip/hip_runtime.h>
#include <hip/hip_bf16.h>

#define BS 32768
#define NWP 10
#define DD 256
#define NEXP 6
#define HH 64
#define OUT_DIM 2
#define MB 64                      // batch items per gemm block
#define WPAD 264                   // W1T LDS row stride in shorts (528B -> 2-way banks)

typedef short bf16x8 __attribute__((ext_vector_type(8)));
typedef float f32x4 __attribute__((ext_vector_type(4)));

__device__ inline short bfs(float f) {
  __hip_bfloat16 h = __float2bfloat16(f);   // RNE
  return __builtin_bit_cast(short, h);
}

// ---------------- kernel 1: bucket batch indices by expert ----------------
__global__ void bucket_k(const int* __restrict__ cmd,
                         int* __restrict__ counts,
                         unsigned short* __restrict__ lists) {
  const int b = blockIdx.x * 256 + threadIdx.x;
  const int e = cmd[b];
  const int lane = threadIdx.x & 63;
  #pragma unroll
  for (int ee = 0; ee < NEXP; ++ee) {
    unsigned long long m = __ballot(e == ee);
    if (e == ee) {
      const int leader = __ffsll((long long)m) - 1;
      const int nbelow = __popcll(m & ((1ull << lane) - 1ull));
      int base = 0;
      if (lane == leader) base = atomicAdd(&counts[ee], __popcll(m));
      base = __shfl(base, leader);   // leader active in branch -> defined
      lists[ee * BS + base + nbelow] = (unsigned short)b;
    }
  }
}

// ------------- kernel 1b: W1 -> W1T bf16 [e][h][d] (pre-transpose) -------------
__global__ void prep_w1t_k(const float* __restrict__ W1, short* __restrict__ W1T) {
  const int e = blockIdx.x;
  const int h = threadIdx.x & 63;
  const int dq = threadIdx.x >> 6;                  // 0..3
  const float* wp = W1 + (size_t)e * DD * HH + h;   // stride HH over d
  short* op = W1T + (size_t)e * HH * DD + (size_t)h * DD;
  #pragma unroll
  for (int j = 0; j < 8; ++j) {
    const int d0 = dq * 64 + j * 8;
    bf16x8 v;
    #pragma unroll
    for (int i = 0; i < 8; ++i) v[i] = bfs(wp[(size_t)(d0 + i) * HH]);
    *(bf16x8*)(op + d0) = v;
  }
}

// -------- kernel 1c: rw[e][n][h] = b1[e][h] + sum_d re[n][d]*W1[e][d][h] --------
__global__ void prep_rew1_k(const float* __restrict__ re,
                            const float* __restrict__ W1,
                            const float* __restrict__ b1,
                            float* __restrict__ rw) {
  const int e = blockIdx.x;
  for (int i = threadIdx.x; i < NWP * HH; i += 256) {
    const int n = i >> 6, h = i & 63;
    const float* rp = re + (size_t)n * DD;
    const float* wp = W1 + (size_t)e * DD * HH + h;
    float s = b1[e * HH + h];
    for (int d = 0; d < DD; ++d) s += rp[d] * wp[(size_t)d * HH];
    rw[((size_t)e * NWP + n) * HH + h] = s;   // fp32, exact
  }
}

// ---------------- kernel 2: barrier-free reg-staged GEMM + cumsum ----------------
__global__ __launch_bounds__(256, 3) void moe_gemm_k(
    const float* __restrict__ x,
    const short* __restrict__ W1T,     // [6][64][256] bf16
    const float* __restrict__ rwg,     // [6][10][64] f32 (b1 folded)
    const float* __restrict__ W2,
    const float* __restrict__ b2,
    const int* __restrict__ counts,
    const unsigned short* __restrict__ lists,
    float* __restrict__ out)
{
  __shared__ short Wt[HH * WPAD];     // 33.0 KB  W1T[e] padded
  __shared__ float rwl[NWP][68];      // 2.72 KB  rw[e] padded (272B rows)
  __shared__ float po[MB * NWP][2];   // 5.12 KB  pre-cumsum outputs

  const int e = blockIdx.y;
  const int cnt = counts[e];
  const int start = blockIdx.x * MB;
  if (start >= cnt) return;
  const int nb = min(MB, cnt - start);
  const int nrows = nb * NWP;

  const int tid = threadIdx.x;
  const int lane = tid & 63;
  const int wv = tid >> 6;
  const int arow = lane & 15;
  const int ag = lane >> 4;

  // stage W1T[e] into LDS (coalesced 16B, once per block)
  {
    const short* src = W1T + (size_t)e * HH * DD;
    for (int i = tid; i < HH * DD / 8; i += 256) {            // 2048 chunks of 8 shorts
      const int h = i >> 5, c = i & 31;
      *(int4*)&Wt[h * WPAD + c * 8] = *(const int4*)(src + h * DD + c * 8);
    }
  }
  for (int i = tid; i < NWP * HH; i += 256)
    rwl[i >> 6][i & 63] = rwg[(size_t)e * NWP * HH + i];

  // all 64 item ids of this block live in the wave's 64 lanes
  int bid_reg = (int)lists[e * BS + start + lane];

  // hoist W2 for this lane's 16 h-values: h(nt,rg) = nt*16 + ag*4 + rg
  float4 w2a[4], w2b[4];
  #pragma unroll
  for (int nt = 0; nt < 4; ++nt) {
    const int h0 = nt * 16 + ag * 4;
    w2a[nt] = *(const float4*)(W2 + ((size_t)e * HH + h0) * OUT_DIM);      // h0:{o0,o1} h1:{o0,o1}
    w2b[nt] = *(const float4*)(W2 + ((size_t)e * HH + h0 + 2) * OUT_DIM);  // h2,h3
  }

  __syncthreads();   // Wt/rwl visible; no more barriers until cumsum

  const int ntile = (nrows + 15) >> 4;
  for (int t = wv; t < ntile; t += 4) {          // tiles disjoint per wave
    const int row = t * 16 + arow;
    const int rowc = min(row, nrows - 1);
    const int item = rowc / NWP;
    const int n = rowc - item * NWP;
    const int gb = __shfl(bid_reg, item);        // per-lane idx, all lanes active

    // 16 x-loads, one base per lane, immediate offsets (16 KB/wave in flight)
    const float4* xb = (const float4*)(x + ((size_t)gb * NWP + n) * DD);
    float4 xs0[8], xs1[8];
    #pragma unroll
    for (int ks = 0; ks < 8; ++ks) { xs0[ks] = xb[ks * 8 + ag * 2]; xs1[ks] = xb[ks * 8 + ag * 2 + 1]; }

    // convert to B-fragments: lane holds x[row][ks*32+ag*8 .. +8)
    bf16x8 bx[8];
    #pragma unroll
    for (int ks = 0; ks < 8; ++ks) {
      bx[ks][0] = bfs(xs0[ks].x); bx[ks][1] = bfs(xs0[ks].y);
      bx[ks][2] = bfs(xs0[ks].z); bx[ks][3] = bfs(xs0[ks].w);
      bx[ks][4] = bfs(xs1[ks].x); bx[ks][5] = bfs(xs1[ks].y);
      bx[ks][6] = bfs(xs1[ks].z); bx[ks][7] = bfs(xs1[ks].w);
    }

    // S^T = W1^T x : acc[nt][rg] -> h = nt*16+ag*4+rg, batch-row = t*16+arow
    f32x4 acc[4] = {{0,0,0,0},{0,0,0,0},{0,0,0,0},{0,0,0,0}};
    #pragma unroll
    for (int ks = 0; ks < 8; ++ks) {
      #pragma unroll
      for (int nt = 0; nt < 4; ++nt) {
        const bf16x8 aw = *(const bf16x8*)&Wt[(nt * 16 + arow) * WPAD + ks * 32 + ag * 8];
        acc[nt] = __builtin_amdgcn_mfma_f32_16x16x32_bf16(aw, bx[ks], acc[nt], 0, 0, 0);
      }
    }

    // epilogue: all 16 h of this lane belong to x-row `rowc` (n known)
    float p0 = 0.f, p1 = 0.f;
    #pragma unroll
    for (int nt = 0; nt < 4; ++nt) {
      const float4 rv = *(const float4*)&rwl[n][nt * 16 + ag * 4];
      const float h0 = fmaxf(acc[nt][0] + rv.x, 0.f);
      const float h1 = fmaxf(acc[nt][1] + rv.y, 0.f);
      const float h2 = fmaxf(acc[nt][2] + rv.z, 0.f);
      const float h3 = fmaxf(acc[nt][3] + rv.w, 0.f);
      p0 += h0 * w2a[nt].x + h1 * w2a[nt].z + h2 * w2b[nt].x + h3 * w2b[nt].z;
      p1 += h0 * w2a[nt].y + h1 * w2a[nt].w + h2 * w2b[nt].y + h3 * w2b[nt].w;
    }
    p0 += __shfl_xor(p0, 16); p1 += __shfl_xor(p1, 16);   // reduce over ag (h-quarters)
    p0 += __shfl_xor(p0, 32); p1 += __shfl_xor(p1, 32);
    if (ag == 0 && row < nrows) {       // unique writer (tiles disjoint per wave)
      po[rowc][0] = p0;
      po[rowc][1] = p1;
    }
  }

  __syncthreads();   // all po stores done

  // fused cumsum + writeout: one thread per batch item
  if (tid < nb) {
    const int gb = (int)lists[e * BS + start + tid];
    const float bb0 = b2[e * OUT_DIM + 0];
    const float bb1 = b2[e * OUT_DIM + 1];
    float v[NWP * OUT_DIM];
    float s0 = 0.f, s1 = 0.f;
    #pragma unroll
    for (int n = 0; n < NWP; ++n) {
      s0 += po[tid * NWP + n][0] + bb0;
      s1 += po[tid * NWP + n][1] + bb1;
      v[n * 2 + 0] = s0;
      v[n * 2 + 1] = s1;
    }
    float4* op = (float4*)(out + (size_t)gb * NWP * OUT_DIM);
    #pragma unroll
    for (int q = 0; q < 5; ++q)
      op[q] = make_float4(v[q * 4], v[q * 4 + 1], v[q * 4 + 2], v[q * 4 + 3]);
  }
}

extern "C" void kernel_launch(void* const* d_in, const int* in_sizes, int n_in,
                              void* d_out, int out_size, void* d_ws, size_t ws_size,
                              hipStream_t stream) {
  const float* x          = (const float*)d_in[0];
  const int*   meas       = (const int*)d_in[1];
  const float* rank_embed = (const float*)d_in[2];
  const float* W1         = (const float*)d_in[3];
  const float* b1         = (const float*)d_in[4];
  const float* W2         = (const float*)d_in[5];
  const float* b2         = (const float*)d_in[6];
  float* out = (float*)d_out;

  int* counts = (int*)d_ws;                                      // @0
  unsigned short* lists = (unsigned short*)((char*)d_ws + 4096); // 384 KB
  short* W1T = (short*)((char*)d_ws + (448 << 10));              // 192 KB bf16
  float* rw  = (float*)((char*)d_ws + (704 << 10));              // 15.4 KB f32

  hipMemsetAsync(d_ws, 0, 256, stream);
  bucket_k<<<BS / 256, 256, 0, stream>>>(meas, counts, lists);
  prep_w1t_k<<<NEXP, 256, 0, stream>>>(W1, W1T);
  prep_rew1_k<<<NEXP, 256, 0, stream>>>(rank_embed, W1, b1, rw);
  dim3 gg((BS + MB - 1) / MB, NEXP);
  moe_gemm_k<<<gg, 256, 0, stream>>>(x, W1T, rw, W2, b2, counts, lists, out);
}

// Round 7
// 147.397 us; speedup vs baseline: 1.2336x; 1.2336x over previous
//
#include <hip/hip_runtime.h>
#include <hip/hip_bf16.h>

#define BS 32768
#define NWP 10
#define DD 256
#define NEXP 6
#define HH 64
#define OUT_DIM 2
#define MB 64                      // batch items per gemm block
#define WPAD 264                   // Wb LDS row stride in shorts (528B)

typedef short bf16x8 __attribute__((ext_vector_type(8)));
typedef float f32x4 __attribute__((ext_vector_type(4)));

__device__ inline short bfs(float f) {
  __hip_bfloat16 h = __float2bfloat16(f);   // RNE
  return __builtin_bit_cast(short, h);
}

// ---------------- kernel 1: bucket batch indices by expert ----------------
__global__ void bucket_k(const int* __restrict__ cmd,
                         int* __restrict__ counts,
                         unsigned short* __restrict__ lists) {
  const int b = blockIdx.x * 256 + threadIdx.x;
  const int e = cmd[b];
  const int lane = threadIdx.x & 63;
  #pragma unroll
  for (int ee = 0; ee < NEXP; ++ee) {
    unsigned long long m = __ballot(e == ee);
    if (e == ee) {
      const int leader = __ffsll((long long)m) - 1;
      const int nbelow = __popcll(m & ((1ull << lane) - 1ull));
      int base = 0;
      if (lane == leader) base = atomicAdd(&counts[ee], __popcll(m));
      base = __shfl(base, leader);   // leader active in branch -> defined
      lists[ee * BS + base + nbelow] = (unsigned short)b;
    }
  }
}

// ---- kernel 1b (fused prep): W1T bf16 [e][h][d]  +  rw[e][n][h]=b1+re·W1 ----
__global__ void prep_k(const float* __restrict__ W1,
                       const float* __restrict__ re,
                       const float* __restrict__ b1,
                       short* __restrict__ W1T,
                       float* __restrict__ rw) {
  const int e = blockIdx.x;
  {
    const int h = threadIdx.x & 63;
    const int dq = threadIdx.x >> 6;                  // 0..3
    const float* wp = W1 + (size_t)e * DD * HH + h;   // stride HH over d
    short* op = W1T + (size_t)e * HH * DD + (size_t)h * DD;
    #pragma unroll
    for (int j = 0; j < 8; ++j) {
      const int d0 = dq * 64 + j * 8;
      bf16x8 v;
      #pragma unroll
      for (int i = 0; i < 8; ++i) v[i] = bfs(wp[(size_t)(d0 + i) * HH]);
      *(bf16x8*)(op + d0) = v;
    }
  }
  for (int i = threadIdx.x; i < NWP * HH; i += 256) {
    const int n = i >> 6, h = i & 63;
    const float* rp = re + (size_t)n * DD;
    const float* wp = W1 + (size_t)e * DD * HH + h;
    float s = b1[e * HH + h];
    for (int d = 0; d < DD; ++d) s += rp[d] * wp[(size_t)d * HH];
    rw[((size_t)e * NWP + n) * HH + h] = s;   // fp32, exact
  }
}

// ------- kernel 2: per-wave independent, barrier-free pipelined GEMM -------
__global__ __launch_bounds__(256, 2) void moe_gemm_k(
    const float* __restrict__ x,
    const short* __restrict__ W1T,     // [6][64][256] bf16
    const float* __restrict__ rwg,     // [6][10][64] f32 (b1 + re·W1)
    const float* __restrict__ W2,
    const float* __restrict__ b2,
    const int* __restrict__ counts,
    const unsigned short* __restrict__ lists,
    float* __restrict__ out)
{
  __shared__ short Wb[HH * WPAD];      // 33.0 KB W1T[e], padded + swizzled
  __shared__ short Xa[4][16 * DD];     // 32.0 KB per-wave 16-row bf16 tiles
  __shared__ float rwl[NWP][68];       // 2.72 KB rw[e]
  __shared__ float w2l[HH * OUT_DIM];  // 0.5 KB  W2[e]
  __shared__ float po[MB * NWP][2];    // 5.12 KB pre-cumsum outputs

  const int e = blockIdx.y;
  const int cnt = counts[e];
  const int start = blockIdx.x * MB;
  if (start >= cnt) return;
  const int nb = min(MB, cnt - start);
  const int nrows = nb * NWP;

  const int tid = threadIdx.x;
  const int lane = tid & 63;
  const int wv = tid >> 6;
  const int arow = lane & 15;
  const int ag = lane >> 4;

  // stage Wb (coalesced 16B chunks; XOR key (h&7)<<3 on short index)
  {
    const short* src = W1T + (size_t)e * HH * DD;
    for (int i = tid; i < HH * DD / 8; i += 256) {
      const int hh = i >> 5;
      const int d = (i & 31) * 8;
      *(int4*)&Wb[hh * WPAD + (d ^ ((hh & 7) << 3))] = *(const int4*)(src + hh * DD + d);
    }
  }
  for (int i = tid; i < NWP * HH; i += 256)
    rwl[i >> 6][i & 63] = rwg[(size_t)e * NWP * HH + i];
  if (tid < HH * OUT_DIM) w2l[tid] = W2[(size_t)e * HH * OUT_DIM + tid];

  int bid_reg = (int)lists[e * BS + start + lane];  // value used only via clamped shfl

  __syncthreads();   // LDS tables ready; NO barriers until cumsum

  short* Xw = &Xa[wv][0];
  const int ntile = (nrows + 15) >> 4;

  float4 xs[16];     // all indices compile-time (rule #20)

  // issue 16 coalesced row-loads for tile t (1KB/instr across the wave)
  auto issue = [&](int t) {
    #pragma unroll
    for (int r = 0; r < 16; ++r) {
      const int rowc = min(t * 16 + r, nrows - 1);
      const int item = rowc / NWP;
      const int nn = rowc - item * NWP;
      const int gb = __shfl(bid_reg, item);   // uniform idx, all lanes active
      xs[r] = *(const float4*)(x + ((size_t)gb * NWP + nn) * DD + lane * 4);
    }
  };
  // cvt + ds_write tile into Xw (write key (r&7)<<3 on short index)
  auto write_tile = [&]() {
    #pragma unroll
    for (int r = 0; r < 16; ++r) {
      short4 pk = make_short4(bfs(xs[r].x), bfs(xs[r].y), bfs(xs[r].z), bfs(xs[r].w));
      *(short4*)&Xw[r * DD + ((lane * 4) ^ ((r & 7) << 3))] = pk;
    }
  };

  issue(wv);   // prologue prefetch (clamped-safe even if wv >= ntile)

  for (int t = wv; t < ntile; t += 4) {
    write_tile();                        // drains xs (compiler vmcnt), DS in-order
    if (t + 4 < ntile) issue(t + 4);     // next tile's 16KB in flight during compute
    __builtin_amdgcn_sched_barrier(0);   // keep load issue above compute

    // compute tile t: S^T = W1^T · x
    f32x4 acc[4] = {{0,0,0,0},{0,0,0,0},{0,0,0,0},{0,0,0,0}};
    #pragma unroll
    for (int ks = 0; ks < 8; ++ks) {
      const int kidx = ks * 32 + ag * 8;
      const bf16x8 bx = *(const bf16x8*)&Xw[arow * DD + (kidx ^ ((arow & 7) << 3))];
      #pragma unroll
      for (int nt = 0; nt < 4; ++nt) {
        const int hh = nt * 16 + arow;
        const bf16x8 aw = *(const bf16x8*)&Wb[hh * WPAD + (kidx ^ ((arow & 7) << 3))];
        acc[nt] = __builtin_amdgcn_mfma_f32_16x16x32_bf16(aw, bx, acc[nt], 0, 0, 0);
      }
    }

    // thin epilogue: lane owns batch-row (t*16+arow), h = nt*16+ag*4+rg
    const int row = t * 16 + arow;
    const int rowc = min(row, nrows - 1);
    const int nn = rowc - (rowc / NWP) * NWP;
    float p0 = 0.f, p1 = 0.f;
    #pragma unroll
    for (int nt = 0; nt < 4; ++nt) {
      const int h0 = nt * 16 + ag * 4;
      const float4 rv = *(const float4*)&rwl[nn][h0];
      const float4 wa = *(const float4*)&w2l[h0 * 2];       // h0:{o0,o1} h1:{o0,o1}
      const float4 wb = *(const float4*)&w2l[h0 * 2 + 4];   // h2,h3
      const float h0v = fmaxf(acc[nt][0] + rv.x, 0.f);
      const float h1v = fmaxf(acc[nt][1] + rv.y, 0.f);
      const float h2v = fmaxf(acc[nt][2] + rv.z, 0.f);
      const float h3v = fmaxf(acc[nt][3] + rv.w, 0.f);
      p0 += h0v * wa.x + h1v * wa.z + h2v * wb.x + h3v * wb.z;
      p1 += h0v * wa.y + h1v * wa.w + h2v * wb.y + h3v * wb.w;
    }
    p0 += __shfl_xor(p0, 16); p1 += __shfl_xor(p1, 16);   // reduce over ag
    p0 += __shfl_xor(p0, 32); p1 += __shfl_xor(p1, 32);
    if (ag == 0 && row < nrows) {   // unique writer: tiles disjoint per wave
      po[row][0] = p0;
      po[row][1] = p1;
    }
  }

  __syncthreads();   // all po stores visible

  // fused cumsum + writeout: one thread per batch item
  if (tid < nb) {
    const int gb = (int)lists[e * BS + start + tid];
    const float bb0 = b2[e * OUT_DIM + 0];
    const float bb1 = b2[e * OUT_DIM + 1];
    float v[NWP * OUT_DIM];
    float s0 = 0.f, s1 = 0.f;
    #pragma unroll
    for (int n = 0; n < NWP; ++n) {
      s0 += po[tid * NWP + n][0] + bb0;
      s1 += po[tid * NWP + n][1] + bb1;
      v[n * 2 + 0] = s0;
      v[n * 2 + 1] = s1;
    }
    float4* op = (float4*)(out + (size_t)gb * NWP * OUT_DIM);
    #pragma unroll
    for (int q = 0; q < 5; ++q)
      op[q] = make_float4(v[q * 4], v[q * 4 + 1], v[q * 4 + 2], v[q * 4 + 3]);
  }
}

extern "C" void kernel_launch(void* const* d_in, const int* in_sizes, int n_in,
                              void* d_out, int out_size, void* d_ws, size_t ws_size,
                              hipStream_t stream) {
  const float* x          = (const float*)d_in[0];
  const int*   meas       = (const int*)d_in[1];
  const float* rank_embed = (const float*)d_in[2];
  const float* W1         = (const float*)d_in[3];
  const float* b1         = (const float*)d_in[4];
  const float* W2         = (const float*)d_in[5];
  const float* b2         = (const float*)d_in[6];
  float* out = (float*)d_out;

  int* counts = (int*)d_ws;                                      // @0
  unsigned short* lists = (unsigned short*)((char*)d_ws + 4096); // 384 KB
  short* W1T = (short*)((char*)d_ws + (448 << 10));              // 192 KB bf16
  float* rw  = (float*)((char*)d_ws + (704 << 10));              // 15.4 KB f32

  hipMemsetAsync(d_ws, 0, 256, stream);
  bucket_k<<<BS / 256, 256, 0, stream>>>(meas, counts, lists);
  prep_k<<<NEXP, 256, 0, stream>>>(W1, rank_embed, b1, W1T, rw);
  dim3 gg((BS + MB - 1) / MB, NEXP);
  moe_gemm_k<<<gg, 256, 0, stream>>>(x, W1T, rw, W2, b2, counts, lists, out);
}

// Round 8
// 113.992 us; speedup vs baseline: 1.5951x; 1.2931x over previous
//
#include <hip/hip_runtime.h>
#include <hip/hip_bf16.h>

#define BS 32768
#define NWP 10
#define DD 256
#define NEXP 6
#define HH 64
#define OUT_DIM 2
#define MB 64

typedef short bf16x8 __attribute__((ext_vector_type(8)));
typedef float f32x4 __attribute__((ext_vector_type(4)));

__device__ inline short bfs(float f) {
  __hip_bfloat16 h = __float2bfloat16(f);   // RNE
  return __builtin_bit_cast(short, h);
}

// ------- kernel 1: bucket by expert (block-aggregated atomics) -------
__global__ __launch_bounds__(1024) void bucket_k(const int* __restrict__ cmd,
                                                 int* __restrict__ counts,
                                                 unsigned short* __restrict__ lists) {
  __shared__ int wcnt[16][NEXP];
  __shared__ int wbase[16][NEXP];
  const int tid = threadIdx.x;
  const int w = tid >> 6, lane = tid & 63;
  const int b = blockIdx.x * 1024 + tid;          // grid covers exactly BS
  const int e = cmd[b];
  #pragma unroll
  for (int ee = 0; ee < NEXP; ++ee) {
    unsigned long long m = __ballot(e == ee);
    if (lane == 0) wcnt[w][ee] = __popcll(m);
  }
  __syncthreads();
  if (tid < NEXP) {
    int tot = 0, pf[16];
    #pragma unroll
    for (int ww = 0; ww < 16; ++ww) { pf[ww] = tot; tot += wcnt[ww][tid]; }
    const int bb = atomicAdd(&counts[tid], tot);  // 6 atomics per block
    #pragma unroll
    for (int ww = 0; ww < 16; ++ww) wbase[ww][tid] = bb + pf[ww];
  }
  __syncthreads();
  #pragma unroll
  for (int ee = 0; ee < NEXP; ++ee) {
    unsigned long long m = __ballot(e == ee);     // same mask as pass 1
    if (e == ee) {
      const int nbelow = __popcll(m & ((1ull << lane) - 1ull));
      lists[ee * BS + wbase[w][ee] + nbelow] = (unsigned short)b;
    }
  }
}

// ------- kernel 1b: prep, 54 blocks. parts 0-7: W1T slice; part 8: rw -------
__global__ void prep_k(const float* __restrict__ W1,
                       const float* __restrict__ re,
                       const float* __restrict__ b1,
                       short* __restrict__ W1T,
                       float* __restrict__ rw) {
  const int e = blockIdx.x;
  const int part = blockIdx.y;
  if (part < 8) {
    const int h = part * 8 + (threadIdx.x >> 5);
    const int d0 = (threadIdx.x & 31) * 8;
    const float* wp = W1 + (size_t)e * DD * HH + h;
    bf16x8 v;
    #pragma unroll
    for (int i = 0; i < 8; ++i) v[i] = bfs(wp[(size_t)(d0 + i) * HH]);
    *(bf16x8*)(W1T + ((size_t)e * HH + h) * DD + d0) = v;
  } else {
    for (int i = threadIdx.x; i < NWP * HH; i += 256) {
      const int n = i >> 6, h = i & 63;
      const float* rp = re + (size_t)n * DD;
      const float* wp = W1 + (size_t)e * DD * HH + h;
      float s = b1[e * HH + h];
      for (int d = 0; d < DD; ++d) s += rp[d] * wp[(size_t)d * HH];
      rw[((size_t)e * NWP + n) * HH + h] = s;     // fp32, exact
    }
  }
}

// ------- kernel 2: R2-skeleton GEMM, W1-frags in registers, fused cumsum -------
__global__ __launch_bounds__(256, 2) void moe_gemm_k(
    const float* __restrict__ x,
    const short* __restrict__ W1T,     // [6][64][256] bf16, L2-resident
    const float* __restrict__ rwg,     // [6][10][64] f32 (b1 + re·W1)
    const float* __restrict__ W2,
    const float* __restrict__ b2,
    const int* __restrict__ counts,
    const unsigned short* __restrict__ lists,
    float* __restrict__ out)
{
  __shared__ short Xa[4][16 * DD];     // 32 KB per-wave single-buffer tiles
  __shared__ float rwl[NWP][68];       // 2.72 KB rw[e]
  __shared__ float w2l[HH * OUT_DIM];  // 0.5 KB  W2[e]
  __shared__ float po[MB * NWP][2];    // 5 KB    pre-cumsum outputs

  const int e = blockIdx.y;
  const int cnt = counts[e];
  const int start = blockIdx.x * MB;
  if (start >= cnt) return;
  const int nb = min(MB, cnt - start);
  const int nrows = nb * NWP;

  const int tid = threadIdx.x;
  const int lane = tid & 63;
  const int wv = tid >> 6;
  const int arow = lane & 15;
  const int ag = lane >> 4;

  // hoist all A-fragments: Wf[nt][ks] = W1T[h=nt*16+arow][ks*32+ag*8 .. +8)
  bf16x8 Wf[4][8];                     // 128 VGPR, static indices only
  {
    const short* wb = W1T + ((size_t)e * HH + arow) * DD + ag * 8;
    #pragma unroll
    for (int nt = 0; nt < 4; ++nt)
      #pragma unroll
      for (int ks = 0; ks < 8; ++ks)
        Wf[nt][ks] = *(const bf16x8*)(wb + (size_t)(nt * 16) * DD + ks * 32);
  }
  for (int i = tid; i < NWP * HH; i += 256)
    rwl[i >> 6][i & 63] = rwg[(size_t)e * NWP * HH + i];
  if (tid < HH * OUT_DIM) w2l[tid] = W2[(size_t)e * HH * OUT_DIM + tid];

  // in-bounds read (lists region fully allocated); garbage lanes never sourced
  int bid_reg = (int)lists[e * BS + start + lane];

  __syncthreads();   // tables ready; no barriers until cumsum

  short* Xw = &Xa[wv][0];
  const int ntile = (nrows + 15) >> 4;

  for (int t = wv; t < ntile; t += 4) {          // tiles disjoint per wave
    // stage 16 rows: coalesced 1KB/instr loads; LLVM pipelines freely
    #pragma unroll
    for (int r = 0; r < 16; ++r) {
      const int rowc = min(t * 16 + r, nrows - 1);
      const int item = rowc / NWP;
      const int nn = rowc - item * NWP;
      const int gb = __shfl(bid_reg, item);      // uniform idx, all lanes active
      const float4 xv = *(const float4*)(x + ((size_t)gb * NWP + nn) * DD + lane * 4);
      short4 pk = make_short4(bfs(xv.x), bfs(xv.y), bfs(xv.z), bfs(xv.w));
      *(short4*)&Xw[r * DD + ((lane * 4) ^ ((r & 7) << 3))] = pk;
    }

    // compute: S^T = W1^T · x ; only 8 ds_reads per tile
    f32x4 acc[4] = {{0,0,0,0},{0,0,0,0},{0,0,0,0},{0,0,0,0}};
    #pragma unroll
    for (int ks = 0; ks < 8; ++ks) {
      const int kidx = ks * 32 + ag * 8;
      const bf16x8 bx = *(const bf16x8*)&Xw[arow * DD + (kidx ^ ((arow & 7) << 3))];
      #pragma unroll
      for (int nt = 0; nt < 4; ++nt)
        acc[nt] = __builtin_amdgcn_mfma_f32_16x16x32_bf16(Wf[nt][ks], bx, acc[nt], 0, 0, 0);
    }

    // thin epilogue: lane owns batch-row t*16+arow; h = nt*16+ag*4+rg
    const int row = t * 16 + arow;
    const int rowc = min(row, nrows - 1);
    const int nn = rowc - (rowc / NWP) * NWP;
    float p0 = 0.f, p1 = 0.f;
    #pragma unroll
    for (int nt = 0; nt < 4; ++nt) {
      const int h0 = nt * 16 + ag * 4;
      const float4 rv = *(const float4*)&rwl[nn][h0];
      const float4 wa = *(const float4*)&w2l[h0 * 2];       // h0:{o0,o1} h1:{o0,o1}
      const float4 wb = *(const float4*)&w2l[h0 * 2 + 4];   // h2,h3
      const float h0v = fmaxf(acc[nt][0] + rv.x, 0.f);
      const float h1v = fmaxf(acc[nt][1] + rv.y, 0.f);
      const float h2v = fmaxf(acc[nt][2] + rv.z, 0.f);
      const float h3v = fmaxf(acc[nt][3] + rv.w, 0.f);
      p0 += h0v * wa.x + h1v * wa.z + h2v * wb.x + h3v * wb.z;
      p1 += h0v * wa.y + h1v * wa.w + h2v * wb.y + h3v * wb.w;
    }
    p0 += __shfl_xor(p0, 16); p1 += __shfl_xor(p1, 16);     // reduce over ag
    p0 += __shfl_xor(p0, 32); p1 += __shfl_xor(p1, 32);
    if (ag == 0 && row < nrows) {     // unique writer: tiles disjoint per wave
      po[row][0] = p0;
      po[row][1] = p1;
    }
  }

  __syncthreads();   // all po stores visible

  // fused cumsum + writeout: one thread per batch item
  if (tid < nb) {
    const int gb = (int)lists[e * BS + start + tid];
    const float bb0 = b2[e * OUT_DIM + 0];
    const float bb1 = b2[e * OUT_DIM + 1];
    float v[NWP * OUT_DIM];
    float s0 = 0.f, s1 = 0.f;
    #pragma unroll
    for (int n = 0; n < NWP; ++n) {
      s0 += po[tid * NWP + n][0] + bb0;
      s1 += po[tid * NWP + n][1] + bb1;
      v[n * 2 + 0] = s0;
      v[n * 2 + 1] = s1;
    }
    float4* op = (float4*)(out + (size_t)gb * NWP * OUT_DIM);
    #pragma unroll
    for (int q = 0; q < 5; ++q)
      op[q] = make_float4(v[q * 4], v[q * 4 + 1], v[q * 4 + 2], v[q * 4 + 3]);
  }
}

extern "C" void kernel_launch(void* const* d_in, const int* in_sizes, int n_in,
                              void* d_out, int out_size, void* d_ws, size_t ws_size,
                              hipStream_t stream) {
  const float* x          = (const float*)d_in[0];
  const int*   meas       = (const int*)d_in[1];
  const float* rank_embed = (const float*)d_in[2];
  const float* W1         = (const float*)d_in[3];
  const float* b1         = (const float*)d_in[4];
  const float* W2         = (const float*)d_in[5];
  const float* b2         = (const float*)d_in[6];
  float* out = (float*)d_out;

  int* counts = (int*)d_ws;                                      // @0
  unsigned short* lists = (unsigned short*)((char*)d_ws + 4096); // 384 KB
  short* W1T = (short*)((char*)d_ws + (448 << 10));              // 192 KB bf16
  float* rw  = (float*)((char*)d_ws + (704 << 10));              // 15.4 KB f32

  hipMemsetAsync(d_ws, 0, 256, stream);
  bucket_k<<<BS / 1024, 1024, 0, stream>>>(meas, counts, lists);
  prep_k<<<dim3(NEXP, 9), 256, 0, stream>>>(W1, rank_embed, b1, W1T, rw);
  dim3 gg((BS + MB - 1) / MB, NEXP);
  moe_gemm_k<<<gg, 256, 0, stream>>>(x, W1T, rw, W2, b2, counts, lists, out);
}